// Round 10
// baseline (13141.388 us; speedup 1.0000x reference)
//
#include <hip/hip_runtime.h>
#include <hip/hip_bf16.h>

#define T_STEPS 2048
#define BATCH   64
#define HID     512
#define GATES   2048   // 4*HID

typedef __attribute__((ext_vector_type(8))) short short8;
typedef __attribute__((ext_vector_type(4))) float f32x4;

__device__ inline unsigned short f2bf(float f) {
  union { float f; unsigned u; } v; v.f = f;
  unsigned r = v.u + 0x7fffu + ((v.u >> 16) & 1u);
  return (unsigned short)(r >> 16);
}
__device__ inline float bf2f(unsigned short s) {
  union { unsigned u; float f; } v; v.u = ((unsigned)s) << 16;
  return v.f;
}
__device__ inline float sigmoidf_(float x) { return 1.f / (1.f + __expf(-x)); }
__device__ inline float tanhf_(float x)    { return 2.f / (1.f + __expf(-2.f * x)) - 1.f; }

// ---------------- Projection GEMM: xg[t][b][g] = A[m] @ W^T + b1 + b2 (bf16 out) ----
template<int ABF16, int TROWS>
__global__ __launch_bounds__(256) void proj_kernel(
    const void* __restrict__ Aptr, const float* __restrict__ W,
    const float* __restrict__ bias1, const float* __restrict__ bias2,
    unsigned short* __restrict__ out)
{
  __shared__ short As[128][72];
  __shared__ short Bs[128][72];
  const int tid  = threadIdx.x;
  const int lane = tid & 63;
  const int wv   = tid >> 6;
  const int wm   = wv >> 1, wn = wv & 1;
  const int bid  = blockIdx.x;
  const int nt   = bid & 15;
  const long mbase = (long)(bid >> 4) * 128;
  const int  nbase = nt * 128;

  f32x4 acc[4][4] = {};

  const int r  = tid >> 1;        // 0..127
  const int kh = (tid & 1) * 32;  // k offset within BK

  for (int kt = 0; kt < 8; ++kt) {
    if (ABF16) {
      const unsigned short* src = (const unsigned short*)Aptr + (mbase + r) * 512 + kt * 64 + kh;
      *(short8*)&As[r][kh]      = *(const short8*)(src);
      *(short8*)&As[r][kh + 8]  = *(const short8*)(src + 8);
      *(short8*)&As[r][kh + 16] = *(const short8*)(src + 16);
      *(short8*)&As[r][kh + 24] = *(const short8*)(src + 24);
    } else {
      const float* src = (const float*)Aptr + (mbase + r) * 512 + kt * 64 + kh;
#pragma unroll
      for (int j = 0; j < 4; ++j) {
        float4 v0 = *(const float4*)(src + j * 8);
        float4 v1 = *(const float4*)(src + j * 8 + 4);
        short8 p;
        p[0] = (short)f2bf(v0.x); p[1] = (short)f2bf(v0.y);
        p[2] = (short)f2bf(v0.z); p[3] = (short)f2bf(v0.w);
        p[4] = (short)f2bf(v1.x); p[5] = (short)f2bf(v1.y);
        p[6] = (short)f2bf(v1.z); p[7] = (short)f2bf(v1.w);
        *(short8*)&As[r][kh + j * 8] = p;
      }
    }
    {
      const float* src = W + (size_t)(nbase + r) * 512 + kt * 64 + kh;
#pragma unroll
      for (int j = 0; j < 4; ++j) {
        float4 v0 = *(const float4*)(src + j * 8);
        float4 v1 = *(const float4*)(src + j * 8 + 4);
        short8 p;
        p[0] = (short)f2bf(v0.x); p[1] = (short)f2bf(v0.y);
        p[2] = (short)f2bf(v0.z); p[3] = (short)f2bf(v0.w);
        p[4] = (short)f2bf(v1.x); p[5] = (short)f2bf(v1.y);
        p[6] = (short)f2bf(v1.z); p[7] = (short)f2bf(v1.w);
        *(short8*)&Bs[r][kh + j * 8] = p;
      }
    }
    __syncthreads();
#pragma unroll
    for (int kk = 0; kk < 2; ++kk) {
      const int kc = kk * 32 + ((lane >> 4) & 3) * 8;
      short8 af[4], bfr[4];
#pragma unroll
      for (int i = 0; i < 4; ++i)
        af[i] = *(const short8*)&As[wm * 64 + i * 16 + (lane & 15)][kc];
#pragma unroll
      for (int i = 0; i < 4; ++i)
        bfr[i] = *(const short8*)&Bs[wn * 64 + i * 16 + (lane & 15)][kc];
#pragma unroll
      for (int i = 0; i < 4; ++i)
#pragma unroll
        for (int j = 0; j < 4; ++j)
          acc[i][j] = __builtin_amdgcn_mfma_f32_16x16x32_bf16(af[i], bfr[j], acc[i][j], 0, 0, 0);
    }
    __syncthreads();
  }
#pragma unroll
  for (int j = 0; j < 4; ++j) {
    const int n = nbase + wn * 64 + j * 16 + (lane & 15);
    const float bsum = bias1[n] + bias2[n];
#pragma unroll
    for (int i = 0; i < 4; ++i) {
      f32x4 v = acc[i][j];
#pragma unroll
      for (int e = 0; e < 4; ++e) {
        long m = mbase + wm * 64 + i * 16 + ((lane >> 4) & 3) * 4 + e;
        long orow = TROWS ? ((m & 2047) * 64 + (m >> 11)) : m;
        out[orow * 2048 + n] = f2bf(v[e] + bsum);
      }
    }
  }
}

// 16 h-fragment loads from PTR (sc0 sc1, L3-coherent), first-half wait (round-3 proven)
#define HLOAD16(PTR)                                                   \
      asm volatile(                                                    \
        "global_load_dwordx4 %0, %16, off sc0 sc1\n\t"                 \
        "global_load_dwordx4 %1, %16, off offset:64 sc0 sc1\n\t"       \
        "global_load_dwordx4 %2, %16, off offset:128 sc0 sc1\n\t"      \
        "global_load_dwordx4 %3, %16, off offset:192 sc0 sc1\n\t"      \
        "global_load_dwordx4 %4, %16, off offset:256 sc0 sc1\n\t"      \
        "global_load_dwordx4 %5, %16, off offset:320 sc0 sc1\n\t"      \
        "global_load_dwordx4 %6, %16, off offset:384 sc0 sc1\n\t"      \
        "global_load_dwordx4 %7, %16, off offset:448 sc0 sc1\n\t"      \
        "global_load_dwordx4 %8, %16, off offset:512 sc0 sc1\n\t"      \
        "global_load_dwordx4 %9, %16, off offset:576 sc0 sc1\n\t"      \
        "global_load_dwordx4 %10, %16, off offset:640 sc0 sc1\n\t"     \
        "global_load_dwordx4 %11, %16, off offset:704 sc0 sc1\n\t"     \
        "global_load_dwordx4 %12, %16, off offset:768 sc0 sc1\n\t"     \
        "global_load_dwordx4 %13, %16, off offset:832 sc0 sc1\n\t"     \
        "global_load_dwordx4 %14, %16, off offset:896 sc0 sc1\n\t"     \
        "global_load_dwordx4 %15, %16, off offset:960 sc0 sc1\n\t"     \
        "s_waitcnt vmcnt(8)"                                           \
        : "=&v"(hh[0]), "=&v"(hh[1]), "=&v"(hh[2]), "=&v"(hh[3]),      \
          "=&v"(hh[4]), "=&v"(hh[5]), "=&v"(hh[6]), "=&v"(hh[7]),      \
          "=&v"(hh[8]), "=&v"(hh[9]), "=&v"(hh[10]), "=&v"(hh[11]),    \
          "=&v"(hh[12]), "=&v"(hh[13]), "=&v"(hh[14]), "=&v"(hh[15])   \
        : "v"(PTR)                                                     \
        : "memory")

// W slice (4 gate types x 32 units of this slice, K=512) -> LDS bf16, XOR-swizzled
__device__ __forceinline__ void load_w_lds(const float* __restrict__ Whh,
                                           int u_base, int tid, char* smem) {
  const int r    = tid >> 1;          // 0..127 slice row
  const int kh   = (tid & 1) * 256;   // k half
  const int type = r >> 5, uu = r & 31;
  const float* src = Whh + (size_t)(type * 512 + u_base + uu) * 512 + kh;
  const int rowbyte = r * 1024;
  const int sw = (r & 7) << 4;
#pragma unroll 4
  for (int j = 0; j < 32; ++j) {
    float4 v0 = *(const float4*)(src + j * 8);
    float4 v1 = *(const float4*)(src + j * 8 + 4);
    short8 p;
    p[0] = (short)f2bf(v0.x); p[1] = (short)f2bf(v0.y);
    p[2] = (short)f2bf(v0.z); p[3] = (short)f2bf(v0.w);
    p[4] = (short)f2bf(v1.x); p[5] = (short)f2bf(v1.y);
    p[6] = (short)f2bf(v1.z); p[7] = (short)f2bf(v1.w);
    int byte = rowbyte + (kh + j * 8) * 2;
    *(short8*)(smem + (byte ^ sw)) = p;
  }
}

// ---------------- scan0: byte-for-byte round-3 protocol (proven 7.54ms) -----------
__device__ void scan0_role(
    int bid0, const unsigned short* __restrict__ xg, const float* __restrict__ Whh,
    unsigned short* __restrict__ hhist, float* __restrict__ dout,
    int* __restrict__ flags, char* smem)
{
  float* gbuf = (float*)(smem + 131072);                // [16][132]
  float* cbuf = (float*)(smem + 131072 + 16 * 132 * 4); // [16][32]
  const int tid  = threadIdx.x;
  const int lane = tid & 63;
  const int wv   = tid >> 6;
  const int s    = bid0 & 15;
  const int grp  = bid0 >> 4;
  const int u_base = s * 32;
  const int b_base = grp * 16;
  int* gflags = flags + grp * (16 * 32);

  load_w_lds(Whh, u_base, tid, smem);
  cbuf[tid] = 0.f; cbuf[tid + 256] = 0.f;
  __syncthreads();

  const int bb = tid >> 4;
  const int u0 = (tid & 15) * 2;
  const int rowA = wv * 32 + (lane & 15);
  const int rowB = rowA + 16;
  const int kb   = ((lane >> 4) & 3) * 16;
  const int swA  = (rowA & 7) << 4;
  const int swB  = (rowB & 7) << 4;

  for (int t = 0; t < T_STEPS; ++t) {
    unsigned xgp[4];
    {
      const size_t base = ((size_t)t * 64 + b_base + bb) * 2048 + u_base + u0;
      xgp[0] = *(const unsigned*)(xg + base);
      xgp[1] = *(const unsigned*)(xg + base + 512);
      xgp[2] = *(const unsigned*)(xg + base + 1024);
      xgp[3] = *(const unsigned*)(xg + base + 1536);
    }

    f32x4 a0a = {0.f, 0.f, 0.f, 0.f}, a1a = {0.f, 0.f, 0.f, 0.f};
    f32x4 a0b = {0.f, 0.f, 0.f, 0.f}, a1b = {0.f, 0.f, 0.f, 0.f};

    if (t > 0) {
      {
        int f;
        do {
          f = __hip_atomic_load(&gflags[(lane & 15) * 32], __ATOMIC_RELAXED, __HIP_MEMORY_SCOPE_AGENT);
        } while (!__all(f >= t));
      }
      const unsigned short* hrow = hhist + (size_t)t * (64 * 512)
          + (size_t)(b_base + (lane & 15)) * 512 + ((lane >> 4) & 3) * 8;
      short8 hh[16];
      HLOAD16(hrow);
      __builtin_amdgcn_sched_barrier(0);

#pragma unroll
      for (int kt = 0; kt < 8; ++kt) {
        short8 b0 = *(const short8*)(smem + ((rowA * 1024 + kt * 64 + kb) ^ swA));
        short8 b1 = *(const short8*)(smem + ((rowB * 1024 + kt * 64 + kb) ^ swB));
        a0a = __builtin_amdgcn_mfma_f32_16x16x32_bf16(hh[kt], b0, a0a, 0, 0, 0);
        a1a = __builtin_amdgcn_mfma_f32_16x16x32_bf16(hh[kt], b1, a1a, 0, 0, 0);
      }
      asm volatile("s_waitcnt vmcnt(0)" ::: "memory");
      __builtin_amdgcn_sched_barrier(0);
#pragma unroll
      for (int kt = 8; kt < 16; ++kt) {
        short8 b0 = *(const short8*)(smem + ((rowA * 1024 + kt * 64 + kb) ^ swA));
        short8 b1 = *(const short8*)(smem + ((rowB * 1024 + kt * 64 + kb) ^ swB));
        a0b = __builtin_amdgcn_mfma_f32_16x16x32_bf16(hh[kt], b0, a0b, 0, 0, 0);
        a1b = __builtin_amdgcn_mfma_f32_16x16x32_bf16(hh[kt], b1, a1b, 0, 0, 0);
      }
    }

    {
      const int m0 = ((lane >> 4) & 3) * 4;
      const int cA = wv * 32 + (lane & 15);
#pragma unroll
      for (int e = 0; e < 4; ++e) {
        gbuf[(m0 + e) * 132 + cA]      = a0a[e] + a0b[e];
        gbuf[(m0 + e) * 132 + cA + 16] = a1a[e] + a1b[e];
      }
    }
    __syncthreads();

    float hv[2], cv[2];
#pragma unroll
    for (int q = 0; q < 2; ++q) {
      const int u = u0 + q;
      float ig = gbuf[bb * 132 + u]        + bf2f((unsigned short)(xgp[0] >> (16 * q)));
      float fg = gbuf[bb * 132 + 32 + u]   + bf2f((unsigned short)(xgp[1] >> (16 * q)));
      float gg = gbuf[bb * 132 + 64 + u]   + bf2f((unsigned short)(xgp[2] >> (16 * q)));
      float og = gbuf[bb * 132 + 96 + u]   + bf2f((unsigned short)(xgp[3] >> (16 * q)));
      float iv = sigmoidf_(ig), fv = sigmoidf_(fg);
      float gv = tanhf_(gg),    ov = sigmoidf_(og);
      float c = fv * cbuf[bb * 32 + u] + iv * gv;
      cbuf[bb * 32 + u] = c;
      float h = ov * tanhf_(c);
      hv[q] = h; cv[q] = c;
    }
    {
      unsigned hp = (unsigned)f2bf(hv[0]) | ((unsigned)f2bf(hv[1]) << 16);
      __hip_atomic_store(
          (unsigned*)(hhist + (size_t)(t + 1) * (64 * 512) + (size_t)(b_base + bb) * 512 + u_base + u0),
          hp, __ATOMIC_RELAXED, __HIP_MEMORY_SCOPE_AGENT);
      if (t == T_STEPS - 1) {
        const size_t OUT0 = (size_t)64 * 2048 * 512;
        size_t o  = OUT0 + (size_t)(b_base + bb) * 512 + u_base + u0;
        dout[o]     = hv[0];
        dout[o + 1] = hv[1];
        size_t oc = o + 65536;
        dout[oc]     = cv[0];
        dout[oc + 1] = cv[1];
      }
    }
    __syncthreads();   // drains vmcnt: h stores acked at coherence point
    if (tid == 0)
      __hip_atomic_store(&gflags[s * 32], t + 1, __ATOMIC_RELAXED, __HIP_MEMORY_SCOPE_AGENT);
  }
}

// ---------------- scan1: chases scan0; input part HOISTED off the critical ring ----
// Step t: (1) poll scan0 flags >= t+1 (scan0 runs ahead -> ~free), load h0[t+1],
// 32 input MFMAs (register weights) — this work hides under the peer-wait window;
// (2) poll own flags >= t, load h1[t], recurrence MFMAs; (3) cell/publish.
__device__ void scan1_role(
    int bid0, const float* __restrict__ Whh1, const float* __restrict__ Wih1,
    const float* __restrict__ bih1, const float* __restrict__ bhh1,
    const unsigned short* __restrict__ h0hist, unsigned short* __restrict__ h1hist,
    float* __restrict__ dout, const int* __restrict__ flg0, int* __restrict__ flg1,
    char* smem)
{
  float* gbuf = (float*)(smem + 131072);                // [16][132]
  float* cbuf = (float*)(smem + 131072 + 16 * 132 * 4); // [16][32]
  const int tid  = threadIdx.x;
  const int lane = tid & 63;
  const int wv   = tid >> 6;
  const int s    = bid0 & 15;
  const int grp  = bid0 >> 4;
  const int u_base = s * 32;
  const int b_base = grp * 16;

  load_w_lds(Whh1, u_base, tid, smem);
  cbuf[tid] = 0.f; cbuf[tid + 256] = 0.f;
  __syncthreads();

  const int bb = tid >> 4;
  const int u0 = (tid & 15) * 2;
  const int rowA = wv * 32 + (lane & 15);
  const int rowB = rowA + 16;
  const int kb   = ((lane >> 4) & 3) * 16;
  const int swA  = (rowA & 7) << 4;
  const int swB  = (rowB & 7) << 4;

  // ---- W_ih1 fragments -> registers (bf16): rows growA/growB, 16 k-steps x 8 elems
  short8 wib0[16], wib1[16];
  {
    const int k0 = ((lane >> 4) & 3) * 8;
    const int growA = (rowA >> 5) * 512 + u_base + (rowA & 31);
    const int growB = (rowB >> 5) * 512 + u_base + (rowB & 31);
#pragma unroll
    for (int kt = 0; kt < 16; ++kt) {
      const float* sA = Wih1 + (size_t)growA * 512 + kt * 32 + k0;
      const float* sB = Wih1 + (size_t)growB * 512 + kt * 32 + k0;
      short8 pa, pb;
#pragma unroll
      for (int e = 0; e < 8; ++e) { pa[e] = (short)f2bf(sA[e]); pb[e] = (short)f2bf(sB[e]); }
      wib0[kt] = pa; wib1[kt] = pb;
    }
  }
  // ---- biases for this thread's two cells (4 gate types x 2 units)
  float bias_[4][2];
#pragma unroll
  for (int ty = 0; ty < 4; ++ty)
#pragma unroll
    for (int q = 0; q < 2; ++q)
      bias_[ty][q] = bih1[ty * 512 + u_base + u0 + q] + bhh1[ty * 512 + u_base + u0 + q];

  const int* p0  = flg0 + (grp * 16 + (lane & 15)) * 32;   // scan0 flags (h0 ready)
  const int* p1  = flg1 + (grp * 16 + (lane & 15)) * 32;   // own-layer peer flags
  int* flp = flg1 + (grp * 16 + s) * 32;

  for (int t = 0; t < T_STEPS; ++t) {
    f32x4 a0a = {0.f, 0.f, 0.f, 0.f}, a1a = {0.f, 0.f, 0.f, 0.f};
    f32x4 a0b = {0.f, 0.f, 0.f, 0.f}, a1b = {0.f, 0.f, 0.f, 0.f};
    short8 hh[16];

    // ---- (1) input part: W_ih1 (registers) @ h0[t+1]; off the critical ring ----
    {
      int f;
      do {
        f = __hip_atomic_load(p0, __ATOMIC_RELAXED, __HIP_MEMORY_SCOPE_AGENT);
      } while (!__all(f >= t + 1));
    }
    {
      const unsigned short* hr0 = h0hist + (size_t)(t + 1) * (64 * 512)
          + (size_t)(b_base + (lane & 15)) * 512 + ((lane >> 4) & 3) * 8;
      HLOAD16(hr0);
      __builtin_amdgcn_sched_barrier(0);
#pragma unroll
      for (int kt = 0; kt < 8; ++kt) {
        a0a = __builtin_amdgcn_mfma_f32_16x16x32_bf16(hh[kt], wib0[kt], a0a, 0, 0, 0);
        a1a = __builtin_amdgcn_mfma_f32_16x16x32_bf16(hh[kt], wib1[kt], a1a, 0, 0, 0);
      }
      asm volatile("s_waitcnt vmcnt(0)" ::: "memory");
      __builtin_amdgcn_sched_barrier(0);
#pragma unroll
      for (int kt = 8; kt < 16; ++kt) {
        a0b = __builtin_amdgcn_mfma_f32_16x16x32_bf16(hh[kt], wib0[kt], a0b, 0, 0, 0);
        a1b = __builtin_amdgcn_mfma_f32_16x16x32_bf16(hh[kt], wib1[kt], a1b, 0, 0, 0);
      }
    }

    // ---- (2) recurrence part: W_hh1 (LDS) @ h1[t]; the critical ring ----
    if (t > 0) {
      {
        int f;
        do {
          f = __hip_atomic_load(p1, __ATOMIC_RELAXED, __HIP_MEMORY_SCOPE_AGENT);
        } while (!__all(f >= t));
      }
      const unsigned short* hr1 = h1hist + (size_t)t * (64 * 512)
          + (size_t)(b_base + (lane & 15)) * 512 + ((lane >> 4) & 3) * 8;
      HLOAD16(hr1);
      __builtin_amdgcn_sched_barrier(0);
#pragma unroll
      for (int kt = 0; kt < 8; ++kt) {
        short8 b0 = *(const short8*)(smem + ((rowA * 1024 + kt * 64 + kb) ^ swA));
        short8 b1 = *(const short8*)(smem + ((rowB * 1024 + kt * 64 + kb) ^ swB));
        a0a = __builtin_amdgcn_mfma_f32_16x16x32_bf16(hh[kt], b0, a0a, 0, 0, 0);
        a1a = __builtin_amdgcn_mfma_f32_16x16x32_bf16(hh[kt], b1, a1a, 0, 0, 0);
      }
      asm volatile("s_waitcnt vmcnt(0)" ::: "memory");
      __builtin_amdgcn_sched_barrier(0);
#pragma unroll
      for (int kt = 8; kt < 16; ++kt) {
        short8 b0 = *(const short8*)(smem + ((rowA * 1024 + kt * 64 + kb) ^ swA));
        short8 b1 = *(const short8*)(smem + ((rowB * 1024 + kt * 64 + kb) ^ swB));
        a0b = __builtin_amdgcn_mfma_f32_16x16x32_bf16(hh[kt], b0, a0b, 0, 0, 0);
        a1b = __builtin_amdgcn_mfma_f32_16x16x32_bf16(hh[kt], b1, a1b, 0, 0, 0);
      }
    }

    {
      const int m0 = ((lane >> 4) & 3) * 4;
      const int cA = wv * 32 + (lane & 15);
#pragma unroll
      for (int e = 0; e < 4; ++e) {
        gbuf[(m0 + e) * 132 + cA]      = a0a[e] + a0b[e];
        gbuf[(m0 + e) * 132 + cA + 16] = a1a[e] + a1b[e];
      }
    }
    __syncthreads();

    float hv[2], cv[2];
#pragma unroll
    for (int q = 0; q < 2; ++q) {
      const int u = u0 + q;
      float ig = gbuf[bb * 132 + u]        + bias_[0][q];
      float fg = gbuf[bb * 132 + 32 + u]   + bias_[1][q];
      float gg = gbuf[bb * 132 + 64 + u]   + bias_[2][q];
      float og = gbuf[bb * 132 + 96 + u]   + bias_[3][q];
      float iv = sigmoidf_(ig), fv = sigmoidf_(fg);
      float gv = tanhf_(gg),    ov = sigmoidf_(og);
      float c = fv * cbuf[bb * 32 + u] + iv * gv;
      cbuf[bb * 32 + u] = c;
      float h = ov * tanhf_(c);
      hv[q] = h; cv[q] = c;
    }
    {
      unsigned hp = (unsigned)f2bf(hv[0]) | ((unsigned)f2bf(hv[1]) << 16);
      __hip_atomic_store(
          (unsigned*)(h1hist + (size_t)(t + 1) * (64 * 512) + (size_t)(b_base + bb) * 512 + u_base + u0),
          hp, __ATOMIC_RELAXED, __HIP_MEMORY_SCOPE_AGENT);
      float2 ho; ho.x = hv[0]; ho.y = hv[1];
      *(float2*)(dout + (size_t)(b_base + bb) * ((size_t)T_STEPS * 512) + (size_t)t * 512 + u_base + u0) = ho;
      if (t == T_STEPS - 1) {
        const size_t OUT0 = (size_t)64 * 2048 * 512;
        size_t o  = OUT0 + 32768 + (size_t)(b_base + bb) * 512 + u_base + u0;
        dout[o]     = hv[0];
        dout[o + 1] = hv[1];
        size_t oc = o + 65536;
        dout[oc]     = cv[0];
        dout[oc + 1] = cv[1];
      }
    }
    __syncthreads();   // drains vmcnt: h1 stores acked at coherence point
    if (tid == 0)
      __hip_atomic_store(flp, t + 1, __ATOMIC_RELAXED, __HIP_MEMORY_SCOPE_AGENT);
  }
}

// ---------------- Fused dual-layer scan: bids 0-63 scan0, 64-127 scan1 -------------
// Deadlock-free unconditionally: scan0 never waits on scan1; all waits are on
// monotonic flags whose producers run unconditionally; 128 WGs @ 1/CU co-resident,
// and even fully-serialized execution would still complete.
__global__ __launch_bounds__(256, 1) void scan_fused(
    const unsigned short* __restrict__ xg,
    const float* __restrict__ Whh0, const float* __restrict__ Whh1,
    const float* __restrict__ Wih1, const float* __restrict__ bih1,
    const float* __restrict__ bhh1,
    unsigned short* __restrict__ h0hist, unsigned short* __restrict__ h1hist,
    float* __restrict__ dout,
    int* __restrict__ flg0, int* __restrict__ flg1)
{
  extern __shared__ char smem[];
  const int bid = blockIdx.x;
  if (bid < 64)
    scan0_role(bid, xg, Whh0, h0hist, dout, flg0, smem);
  else
    scan1_role(bid - 64, Whh1, Wih1, bih1, bhh1, h0hist, h1hist, dout, flg0, flg1, smem);
}

extern "C" void kernel_launch(void* const* d_in, const int* in_sizes, int n_in,
                              void* d_out, int out_size, void* d_ws, size_t ws_size,
                              hipStream_t stream) {
  const float* x    = (const float*)d_in[0];
  const float* Wih0 = (const float*)d_in[1];
  const float* Whh0 = (const float*)d_in[2];
  const float* bih0 = (const float*)d_in[3];
  const float* bhh0 = (const float*)d_in[4];
  const float* Wih1 = (const float*)d_in[5];
  const float* Whh1 = (const float*)d_in[6];
  const float* bih1 = (const float*)d_in[7];
  const float* bhh1 = (const float*)d_in[8];
  float* out = (float*)d_out;

  const size_t XG_BYTES   = (size_t)T_STEPS * 64 * 2048 * 2;       // 536,870,912
  const size_t H_BYTES    = (size_t)(T_STEPS + 1) * 64 * 512 * 2;  // 134,283,264
  const size_t FLAG_BYTES = (size_t)2 * 4 * 16 * 32 * 4;           // 16,384 (128B/flag)
  if (ws_size < XG_BYTES + 2 * H_BYTES + FLAG_BYTES) return;

  char* ws = (char*)d_ws;
  unsigned short* xg = (unsigned short*)ws;
  unsigned short* h0 = (unsigned short*)(ws + XG_BYTES);
  unsigned short* h1 = (unsigned short*)(ws + XG_BYTES + H_BYTES);
  int* flags         = (int*)(ws + XG_BYTES + 2 * H_BYTES);
  int* flg0 = flags;
  int* flg1 = flags + 4 * 16 * 32;

  hipMemsetAsync(flags, 0, FLAG_BYTES, stream);

  const int smem_scan = 131072 + 16 * 132 * 4 + 2048;  // 141,568 B
  hipFuncSetAttribute((const void*)scan_fused, hipFuncAttributeMaxDynamicSharedMemorySize, smem_scan);

  proj_kernel<0, 1><<<dim3(16384), dim3(256), 0, stream>>>(x, Wih0, bih0, bhh0, xg);
  scan_fused<<<dim3(128), dim3(256), smem_scan, stream>>>(
      xg, Whh0, Whh1, Wih1, bih1, bhh1, h0, h1, out, flg0, flg1);
}

// Round 11
// 12379.111 us; speedup vs baseline: 1.0616x; 1.0616x over previous
//
#include <hip/hip_runtime.h>
#include <hip/hip_bf16.h>

#define T_STEPS 2048
#define BATCH   64
#define HID     512
#define GATES   2048   // 4*HID

typedef __attribute__((ext_vector_type(8))) short short8;
typedef __attribute__((ext_vector_type(4))) float f32x4;

__device__ inline unsigned short f2bf(float f) {
  union { float f; unsigned u; } v; v.f = f;
  unsigned r = v.u + 0x7fffu + ((v.u >> 16) & 1u);
  return (unsigned short)(r >> 16);
}
__device__ inline float bf2f(unsigned short s) {
  union { unsigned u; float f; } v; v.u = ((unsigned)s) << 16;
  return v.f;
}
__device__ inline float sigmoidf_(float x) { return 1.f / (1.f + __expf(-x)); }
__device__ inline float tanhf_(float x)    { return 2.f / (1.f + __expf(-2.f * x)) - 1.f; }

// ---------------- Projection GEMM: xg[t][b][g] = A[m] @ W^T + b1 + b2 (bf16 out) ----
template<int ABF16, int TROWS>
__global__ __launch_bounds__(256) void proj_kernel(
    const void* __restrict__ Aptr, const float* __restrict__ W,
    const float* __restrict__ bias1, const float* __restrict__ bias2,
    unsigned short* __restrict__ out)
{
  __shared__ short As[128][72];
  __shared__ short Bs[128][72];
  const int tid  = threadIdx.x;
  const int lane = tid & 63;
  const int wv   = tid >> 6;
  const int wm   = wv >> 1, wn = wv & 1;
  const int bid  = blockIdx.x;
  const int nt   = bid & 15;
  const long mbase = (long)(bid >> 4) * 128;
  const int  nbase = nt * 128;

  f32x4 acc[4][4] = {};

  const int r  = tid >> 1;        // 0..127
  const int kh = (tid & 1) * 32;  // k offset within BK

  for (int kt = 0; kt < 8; ++kt) {
    if (ABF16) {
      const unsigned short* src = (const unsigned short*)Aptr + (mbase + r) * 512 + kt * 64 + kh;
      *(short8*)&As[r][kh]      = *(const short8*)(src);
      *(short8*)&As[r][kh + 8]  = *(const short8*)(src + 8);
      *(short8*)&As[r][kh + 16] = *(const short8*)(src + 16);
      *(short8*)&As[r][kh + 24] = *(const short8*)(src + 24);
    } else {
      const float* src = (const float*)Aptr + (mbase + r) * 512 + kt * 64 + kh;
#pragma unroll
      for (int j = 0; j < 4; ++j) {
        float4 v0 = *(const float4*)(src + j * 8);
        float4 v1 = *(const float4*)(src + j * 8 + 4);
        short8 p;
        p[0] = (short)f2bf(v0.x); p[1] = (short)f2bf(v0.y);
        p[2] = (short)f2bf(v0.z); p[3] = (short)f2bf(v0.w);
        p[4] = (short)f2bf(v1.x); p[5] = (short)f2bf(v1.y);
        p[6] = (short)f2bf(v1.z); p[7] = (short)f2bf(v1.w);
        *(short8*)&As[r][kh + j * 8] = p;
      }
    }
    {
      const float* src = W + (size_t)(nbase + r) * 512 + kt * 64 + kh;
#pragma unroll
      for (int j = 0; j < 4; ++j) {
        float4 v0 = *(const float4*)(src + j * 8);
        float4 v1 = *(const float4*)(src + j * 8 + 4);
        short8 p;
        p[0] = (short)f2bf(v0.x); p[1] = (short)f2bf(v0.y);
        p[2] = (short)f2bf(v0.z); p[3] = (short)f2bf(v0.w);
        p[4] = (short)f2bf(v1.x); p[5] = (short)f2bf(v1.y);
        p[6] = (short)f2bf(v1.z); p[7] = (short)f2bf(v1.w);
        *(short8*)&Bs[r][kh + j * 8] = p;
      }
    }
    __syncthreads();
#pragma unroll
    for (int kk = 0; kk < 2; ++kk) {
      const int kc = kk * 32 + ((lane >> 4) & 3) * 8;
      short8 af[4], bfr[4];
#pragma unroll
      for (int i = 0; i < 4; ++i)
        af[i] = *(const short8*)&As[wm * 64 + i * 16 + (lane & 15)][kc];
#pragma unroll
      for (int i = 0; i < 4; ++i)
        bfr[i] = *(const short8*)&Bs[wn * 64 + i * 16 + (lane & 15)][kc];
#pragma unroll
      for (int i = 0; i < 4; ++i)
#pragma unroll
        for (int j = 0; j < 4; ++j)
          acc[i][j] = __builtin_amdgcn_mfma_f32_16x16x32_bf16(af[i], bfr[j], acc[i][j], 0, 0, 0);
    }
    __syncthreads();
  }
#pragma unroll
  for (int j = 0; j < 4; ++j) {
    const int n = nbase + wn * 64 + j * 16 + (lane & 15);
    const float bsum = bias1[n] + bias2[n];
#pragma unroll
    for (int i = 0; i < 4; ++i) {
      f32x4 v = acc[i][j];
#pragma unroll
      for (int e = 0; e < 4; ++e) {
        long m = mbase + wm * 64 + i * 16 + ((lane >> 4) & 3) * 4 + e;
        long orow = TROWS ? ((m & 2047) * 64 + (m >> 11)) : m;
        out[orow * 2048 + n] = f2bf(v[e] + bsum);
      }
    }
  }
}

// 16 h-fragment loads into ARR, with first-half wait (round-3 proven, scan0 path)
#define HLOAD16W(ARR, PTR)                                             \
      asm volatile(                                                    \
        "global_load_dwordx4 %0, %16, off sc0 sc1\n\t"                 \
        "global_load_dwordx4 %1, %16, off offset:64 sc0 sc1\n\t"       \
        "global_load_dwordx4 %2, %16, off offset:128 sc0 sc1\n\t"      \
        "global_load_dwordx4 %3, %16, off offset:192 sc0 sc1\n\t"      \
        "global_load_dwordx4 %4, %16, off offset:256 sc0 sc1\n\t"      \
        "global_load_dwordx4 %5, %16, off offset:320 sc0 sc1\n\t"      \
        "global_load_dwordx4 %6, %16, off offset:384 sc0 sc1\n\t"      \
        "global_load_dwordx4 %7, %16, off offset:448 sc0 sc1\n\t"      \
        "global_load_dwordx4 %8, %16, off offset:512 sc0 sc1\n\t"      \
        "global_load_dwordx4 %9, %16, off offset:576 sc0 sc1\n\t"      \
        "global_load_dwordx4 %10, %16, off offset:640 sc0 sc1\n\t"     \
        "global_load_dwordx4 %11, %16, off offset:704 sc0 sc1\n\t"     \
        "global_load_dwordx4 %12, %16, off offset:768 sc0 sc1\n\t"     \
        "global_load_dwordx4 %13, %16, off offset:832 sc0 sc1\n\t"     \
        "global_load_dwordx4 %14, %16, off offset:896 sc0 sc1\n\t"     \
        "global_load_dwordx4 %15, %16, off offset:960 sc0 sc1\n\t"     \
        "s_waitcnt vmcnt(8)"                                           \
        : "=&v"(ARR[0]), "=&v"(ARR[1]), "=&v"(ARR[2]), "=&v"(ARR[3]),  \
          "=&v"(ARR[4]), "=&v"(ARR[5]), "=&v"(ARR[6]), "=&v"(ARR[7]),  \
          "=&v"(ARR[8]), "=&v"(ARR[9]), "=&v"(ARR[10]), "=&v"(ARR[11]),\
          "=&v"(ARR[12]), "=&v"(ARR[13]), "=&v"(ARR[14]), "=&v"(ARR[15])\
        : "v"(PTR)                                                     \
        : "memory")

// 16 h-fragment loads into ARR, issue only (NO wait) — retired by a later vmcnt
#define HLOAD16I(ARR, PTR)                                             \
      asm volatile(                                                    \
        "global_load_dwordx4 %0, %16, off sc0 sc1\n\t"                 \
        "global_load_dwordx4 %1, %16, off offset:64 sc0 sc1\n\t"       \
        "global_load_dwordx4 %2, %16, off offset:128 sc0 sc1\n\t"      \
        "global_load_dwordx4 %3, %16, off offset:192 sc0 sc1\n\t"      \
        "global_load_dwordx4 %4, %16, off offset:256 sc0 sc1\n\t"      \
        "global_load_dwordx4 %5, %16, off offset:320 sc0 sc1\n\t"      \
        "global_load_dwordx4 %6, %16, off offset:384 sc0 sc1\n\t"      \
        "global_load_dwordx4 %7, %16, off offset:448 sc0 sc1\n\t"      \
        "global_load_dwordx4 %8, %16, off offset:512 sc0 sc1\n\t"      \
        "global_load_dwordx4 %9, %16, off offset:576 sc0 sc1\n\t"      \
        "global_load_dwordx4 %10, %16, off offset:640 sc0 sc1\n\t"     \
        "global_load_dwordx4 %11, %16, off offset:704 sc0 sc1\n\t"     \
        "global_load_dwordx4 %12, %16, off offset:768 sc0 sc1\n\t"     \
        "global_load_dwordx4 %13, %16, off offset:832 sc0 sc1\n\t"     \
        "global_load_dwordx4 %14, %16, off offset:896 sc0 sc1\n\t"     \
        "global_load_dwordx4 %15, %16, off offset:960 sc0 sc1"         \
        : "=&v"(ARR[0]), "=&v"(ARR[1]), "=&v"(ARR[2]), "=&v"(ARR[3]),  \
          "=&v"(ARR[4]), "=&v"(ARR[5]), "=&v"(ARR[6]), "=&v"(ARR[7]),  \
          "=&v"(ARR[8]), "=&v"(ARR[9]), "=&v"(ARR[10]), "=&v"(ARR[11]),\
          "=&v"(ARR[12]), "=&v"(ARR[13]), "=&v"(ARR[14]), "=&v"(ARR[15])\
        : "v"(PTR)                                                     \
        : "memory")

// W slice (4 gate types x 32 units of this slice, K=512) -> LDS bf16, XOR-swizzled
__device__ __forceinline__ void load_w_lds(const float* __restrict__ Whh,
                                           int u_base, int tid, char* smem) {
  const int r    = tid >> 1;          // 0..127 slice row
  const int kh   = (tid & 1) * 256;   // k half
  const int type = r >> 5, uu = r & 31;
  const float* src = Whh + (size_t)(type * 512 + u_base + uu) * 512 + kh;
  const int rowbyte = r * 1024;
  const int sw = (r & 7) << 4;
#pragma unroll 4
  for (int j = 0; j < 32; ++j) {
    float4 v0 = *(const float4*)(src + j * 8);
    float4 v1 = *(const float4*)(src + j * 8 + 4);
    short8 p;
    p[0] = (short)f2bf(v0.x); p[1] = (short)f2bf(v0.y);
    p[2] = (short)f2bf(v0.z); p[3] = (short)f2bf(v0.w);
    p[4] = (short)f2bf(v1.x); p[5] = (short)f2bf(v1.y);
    p[6] = (short)f2bf(v1.z); p[7] = (short)f2bf(v1.w);
    int byte = rowbyte + (kh + j * 8) * 2;
    *(short8*)(smem + (byte ^ sw)) = p;
  }
}

// ---------------- scan0: byte-for-byte round-3 protocol (proven 7.54ms) -----------
__device__ void scan0_role(
    int bid0, const unsigned short* __restrict__ xg, const float* __restrict__ Whh,
    unsigned short* __restrict__ hhist, float* __restrict__ dout,
    int* __restrict__ flags, char* smem)
{
  float* gbuf = (float*)(smem + 131072);                // [16][132]
  float* cbuf = (float*)(smem + 131072 + 16 * 132 * 4); // [16][32]
  const int tid  = threadIdx.x;
  const int lane = tid & 63;
  const int wv   = tid >> 6;
  const int s    = bid0 & 15;
  const int grp  = bid0 >> 4;
  const int u_base = s * 32;
  const int b_base = grp * 16;
  int* gflags = flags + grp * (16 * 32);

  load_w_lds(Whh, u_base, tid, smem);
  cbuf[tid] = 0.f; cbuf[tid + 256] = 0.f;
  __syncthreads();

  const int bb = tid >> 4;
  const int u0 = (tid & 15) * 2;
  const int rowA = wv * 32 + (lane & 15);
  const int rowB = rowA + 16;
  const int kb   = ((lane >> 4) & 3) * 16;
  const int swA  = (rowA & 7) << 4;
  const int swB  = (rowB & 7) << 4;

  for (int t = 0; t < T_STEPS; ++t) {
    unsigned xgp[4];
    {
      const size_t base = ((size_t)t * 64 + b_base + bb) * 2048 + u_base + u0;
      xgp[0] = *(const unsigned*)(xg + base);
      xgp[1] = *(const unsigned*)(xg + base + 512);
      xgp[2] = *(const unsigned*)(xg + base + 1024);
      xgp[3] = *(const unsigned*)(xg + base + 1536);
    }

    f32x4 a0a = {0.f, 0.f, 0.f, 0.f}, a1a = {0.f, 0.f, 0.f, 0.f};
    f32x4 a0b = {0.f, 0.f, 0.f, 0.f}, a1b = {0.f, 0.f, 0.f, 0.f};

    if (t > 0) {
      {
        int f;
        do {
          f = __hip_atomic_load(&gflags[(lane & 15) * 32], __ATOMIC_RELAXED, __HIP_MEMORY_SCOPE_AGENT);
        } while (!__all(f >= t));
      }
      const unsigned short* hrow = hhist + (size_t)t * (64 * 512)
          + (size_t)(b_base + (lane & 15)) * 512 + ((lane >> 4) & 3) * 8;
      short8 hh[16];
      HLOAD16W(hh, hrow);
      __builtin_amdgcn_sched_barrier(0);

#pragma unroll
      for (int kt = 0; kt < 8; ++kt) {
        short8 b0 = *(const short8*)(smem + ((rowA * 1024 + kt * 64 + kb) ^ swA));
        short8 b1 = *(const short8*)(smem + ((rowB * 1024 + kt * 64 + kb) ^ swB));
        a0a = __builtin_amdgcn_mfma_f32_16x16x32_bf16(hh[kt], b0, a0a, 0, 0, 0);
        a1a = __builtin_amdgcn_mfma_f32_16x16x32_bf16(hh[kt], b1, a1a, 0, 0, 0);
      }
      asm volatile("s_waitcnt vmcnt(0)" ::: "memory");
      __builtin_amdgcn_sched_barrier(0);
#pragma unroll
      for (int kt = 8; kt < 16; ++kt) {
        short8 b0 = *(const short8*)(smem + ((rowA * 1024 + kt * 64 + kb) ^ swA));
        short8 b1 = *(const short8*)(smem + ((rowB * 1024 + kt * 64 + kb) ^ swB));
        a0b = __builtin_amdgcn_mfma_f32_16x16x32_bf16(hh[kt], b0, a0b, 0, 0, 0);
        a1b = __builtin_amdgcn_mfma_f32_16x16x32_bf16(hh[kt], b1, a1b, 0, 0, 0);
      }
    }

    {
      const int m0 = ((lane >> 4) & 3) * 4;
      const int cA = wv * 32 + (lane & 15);
#pragma unroll
      for (int e = 0; e < 4; ++e) {
        gbuf[(m0 + e) * 132 + cA]      = a0a[e] + a0b[e];
        gbuf[(m0 + e) * 132 + cA + 16] = a1a[e] + a1b[e];
      }
    }
    __syncthreads();

    float hv[2], cv[2];
#pragma unroll
    for (int q = 0; q < 2; ++q) {
      const int u = u0 + q;
      float ig = gbuf[bb * 132 + u]        + bf2f((unsigned short)(xgp[0] >> (16 * q)));
      float fg = gbuf[bb * 132 + 32 + u]   + bf2f((unsigned short)(xgp[1] >> (16 * q)));
      float gg = gbuf[bb * 132 + 64 + u]   + bf2f((unsigned short)(xgp[2] >> (16 * q)));
      float og = gbuf[bb * 132 + 96 + u]   + bf2f((unsigned short)(xgp[3] >> (16 * q)));
      float iv = sigmoidf_(ig), fv = sigmoidf_(fg);
      float gv = tanhf_(gg),    ov = sigmoidf_(og);
      float c = fv * cbuf[bb * 32 + u] + iv * gv;
      cbuf[bb * 32 + u] = c;
      float h = ov * tanhf_(c);
      hv[q] = h; cv[q] = c;
    }
    {
      unsigned hp = (unsigned)f2bf(hv[0]) | ((unsigned)f2bf(hv[1]) << 16);
      __hip_atomic_store(
          (unsigned*)(hhist + (size_t)(t + 1) * (64 * 512) + (size_t)(b_base + bb) * 512 + u_base + u0),
          hp, __ATOMIC_RELAXED, __HIP_MEMORY_SCOPE_AGENT);
      if (t == T_STEPS - 1) {
        const size_t OUT0 = (size_t)64 * 2048 * 512;
        size_t o  = OUT0 + (size_t)(b_base + bb) * 512 + u_base + u0;
        dout[o]     = hv[0];
        dout[o + 1] = hv[1];
        size_t oc = o + 65536;
        dout[oc]     = cv[0];
        dout[oc + 1] = cv[1];
      }
    }
    __syncthreads();   // drains vmcnt: h stores acked at coherence point
    if (tid == 0)
      __hip_atomic_store(&gflags[s * 32], t + 1, __ATOMIC_RELAXED, __HIP_MEMORY_SCOPE_AGENT);
  }
}

// ---------------- scan1: h0 loads issued UNDER the merged poll ---------------------
// Invariant entering step t: scan0 flags >= t+1 (verified at step t-1 via the
// merged poll's scan0 >= min(t+2,T) condition; t=0 via pre-loop poll). So:
// issue h0[t+1] loads -> merged poll (own>=t || scan0>=min(t+2,T)); each poll
// iteration's vmcnt(0) retires the h0 loads under the flag wait -> issue h1[t]
// -> input MFMAs (reg weights, h1 in flight) -> staged rec MFMAs -> cell.
__device__ void scan1_role(
    int bid0, const float* __restrict__ Whh1, const float* __restrict__ Wih1,
    const float* __restrict__ bih1, const float* __restrict__ bhh1,
    const unsigned short* __restrict__ h0hist, unsigned short* __restrict__ h1hist,
    float* __restrict__ dout, const int* __restrict__ flg0, int* __restrict__ flg1,
    char* smem)
{
  float* gbuf = (float*)(smem + 131072);                // [16][132]
  float* cbuf = (float*)(smem + 131072 + 16 * 132 * 4); // [16][32]
  const int tid  = threadIdx.x;
  const int lane = tid & 63;
  const int wv   = tid >> 6;
  const int s    = bid0 & 15;
  const int grp  = bid0 >> 4;
  const int u_base = s * 32;
  const int b_base = grp * 16;

  load_w_lds(Whh1, u_base, tid, smem);
  cbuf[tid] = 0.f; cbuf[tid + 256] = 0.f;
  __syncthreads();

  const int bb = tid >> 4;
  const int u0 = (tid & 15) * 2;
  const int rowA = wv * 32 + (lane & 15);
  const int rowB = rowA + 16;
  const int kb   = ((lane >> 4) & 3) * 16;
  const int swA  = (rowA & 7) << 4;
  const int swB  = (rowB & 7) << 4;

  // ---- W_ih1 fragments -> registers (bf16): rows growA/growB, 16 k-steps x 8 elems
  short8 wib0[16], wib1[16];
  {
    const int k0 = ((lane >> 4) & 3) * 8;
    const int growA = (rowA >> 5) * 512 + u_base + (rowA & 31);
    const int growB = (rowB >> 5) * 512 + u_base + (rowB & 31);
#pragma unroll
    for (int kt = 0; kt < 16; ++kt) {
      const float* sA = Wih1 + (size_t)growA * 512 + kt * 32 + k0;
      const float* sB = Wih1 + (size_t)growB * 512 + kt * 32 + k0;
      short8 pa, pb;
#pragma unroll
      for (int e = 0; e < 8; ++e) { pa[e] = (short)f2bf(sA[e]); pb[e] = (short)f2bf(sB[e]); }
      wib0[kt] = pa; wib1[kt] = pb;
    }
  }
  // ---- biases for this thread's two cells (4 gate types x 2 units)
  float bias_[4][2];
#pragma unroll
  for (int ty = 0; ty < 4; ++ty)
#pragma unroll
    for (int q = 0; q < 2; ++q)
      bias_[ty][q] = bih1[ty * 512 + u_base + u0 + q] + bhh1[ty * 512 + u_base + u0 + q];

  // merged poll pointers (round-9 proven split): lanes 0-15 own flags, 16-31 scan0
  const int pl = lane & 31;
  const int* pollp = (pl < 16) ? (flg1 + (grp * 16 + pl) * 32)
                               : (flg0 + (grp * 16 + (pl - 16)) * 32);
  const int* p0 = flg0 + (grp * 16 + (lane & 15)) * 32;
  int* flp = flg1 + (grp * 16 + s) * 32;

  // ---- pre-loop: establish invariant scan0 >= 1 before first h0 issue ----
  {
    int f;
    do {
      f = __hip_atomic_load(p0, __ATOMIC_RELAXED, __HIP_MEMORY_SCOPE_AGENT);
    } while (!__all(f >= 1));
  }

  for (int t = 0; t < T_STEPS; ++t) {
    // ---- issue h0[t+1] loads (valid by invariant); retired under the poll ----
    short8 gg[16];
    {
      const unsigned short* hr0 = h0hist + (size_t)(t + 1) * (64 * 512)
          + (size_t)(b_base + (lane & 15)) * 512 + ((lane >> 4) & 3) * 8;
      HLOAD16I(gg, hr0);
    }
    // ---- merged poll: own >= t AND scan0 >= min(t+2, T) (next step's invariant).
    // Each iteration's compiler-emitted vmcnt(0) retires the gg loads for free.
    {
      const int need = (pl < 16) ? t : ((t + 2 < T_STEPS) ? t + 2 : T_STEPS);
      int f;
      do {
        f = __hip_atomic_load(pollp, __ATOMIC_RELAXED, __HIP_MEMORY_SCOPE_AGENT);
      } while (!__all(f >= need));
    }
    asm volatile("s_waitcnt vmcnt(0)" ::: "memory");   // gg guaranteed resident
    __builtin_amdgcn_sched_barrier(0);                 // rule #18 fence

    f32x4 a0a = {0.f, 0.f, 0.f, 0.f}, a1a = {0.f, 0.f, 0.f, 0.f};
    f32x4 a0b = {0.f, 0.f, 0.f, 0.f}, a1b = {0.f, 0.f, 0.f, 0.f};
    short8 hh[16];

    if (t > 0) {
      // issue h1[t] loads; they fly under the input MFMAs below
      const unsigned short* hr1 = h1hist + (size_t)t * (64 * 512)
          + (size_t)(b_base + (lane & 15)) * 512 + ((lane >> 4) & 3) * 8;
      HLOAD16I(hh, hr1);
      __builtin_amdgcn_sched_barrier(0);
    }

    // ---- input MFMAs: W_ih1 (registers) @ h0[t+1]; h1 loads in flight ----
#pragma unroll
    for (int kt = 0; kt < 8; ++kt) {
      a0a = __builtin_amdgcn_mfma_f32_16x16x32_bf16(gg[kt], wib0[kt], a0a, 0, 0, 0);
      a1a = __builtin_amdgcn_mfma_f32_16x16x32_bf16(gg[kt], wib1[kt], a1a, 0, 0, 0);
    }
#pragma unroll
    for (int kt = 8; kt < 16; ++kt) {
      a0b = __builtin_amdgcn_mfma_f32_16x16x32_bf16(gg[kt], wib0[kt], a0b, 0, 0, 0);
      a1b = __builtin_amdgcn_mfma_f32_16x16x32_bf16(gg[kt], wib1[kt], a1b, 0, 0, 0);
    }

    if (t > 0) {
      // ---- recurrence MFMAs: W_hh1 (LDS) @ h1[t], staged on h1 arrival ----
      asm volatile("s_waitcnt vmcnt(8)" ::: "memory");
      __builtin_amdgcn_sched_barrier(0);
#pragma unroll
      for (int kt = 0; kt < 8; ++kt) {
        short8 b0 = *(const short8*)(smem + ((rowA * 1024 + kt * 64 + kb) ^ swA));
        short8 b1 = *(const short8*)(smem + ((rowB * 1024 + kt * 64 + kb) ^ swB));
        a0a = __builtin_amdgcn_mfma_f32_16x16x32_bf16(hh[kt], b0, a0a, 0, 0, 0);
        a1a = __builtin_amdgcn_mfma_f32_16x16x32_bf16(hh[kt], b1, a1a, 0, 0, 0);
      }
      asm volatile("s_waitcnt vmcnt(0)" ::: "memory");
      __builtin_amdgcn_sched_barrier(0);
#pragma unroll
      for (int kt = 8; kt < 16; ++kt) {
        short8 b0 = *(const short8*)(smem + ((rowA * 1024 + kt * 64 + kb) ^ swA));
        short8 b1 = *(const short8*)(smem + ((rowB * 1024 + kt * 64 + kb) ^ swB));
        a0b = __builtin_amdgcn_mfma_f32_16x16x32_bf16(hh[kt], b0, a0b, 0, 0, 0);
        a1b = __builtin_amdgcn_mfma_f32_16x16x32_bf16(hh[kt], b1, a1b, 0, 0, 0);
      }
    }

    {
      const int m0 = ((lane >> 4) & 3) * 4;
      const int cA = wv * 32 + (lane & 15);
#pragma unroll
      for (int e = 0; e < 4; ++e) {
        gbuf[(m0 + e) * 132 + cA]      = a0a[e] + a0b[e];
        gbuf[(m0 + e) * 132 + cA + 16] = a1a[e] + a1b[e];
      }
    }
    __syncthreads();

    float hv[2], cv[2];
#pragma unroll
    for (int q = 0; q < 2; ++q) {
      const int u = u0 + q;
      float ig = gbuf[bb * 132 + u]        + bias_[0][q];
      float fg = gbuf[bb * 132 + 32 + u]   + bias_[1][q];
      float gg2 = gbuf[bb * 132 + 64 + u]  + bias_[2][q];
      float og = gbuf[bb * 132 + 96 + u]   + bias_[3][q];
      float iv = sigmoidf_(ig), fv = sigmoidf_(fg);
      float gv = tanhf_(gg2),   ov = sigmoidf_(og);
      float c = fv * cbuf[bb * 32 + u] + iv * gv;
      cbuf[bb * 32 + u] = c;
      float h = ov * tanhf_(c);
      hv[q] = h; cv[q] = c;
    }
    {
      unsigned hp = (unsigned)f2bf(hv[0]) | ((unsigned)f2bf(hv[1]) << 16);
      __hip_atomic_store(
          (unsigned*)(h1hist + (size_t)(t + 1) * (64 * 512) + (size_t)(b_base + bb) * 512 + u_base + u0),
          hp, __ATOMIC_RELAXED, __HIP_MEMORY_SCOPE_AGENT);
      float2 ho; ho.x = hv[0]; ho.y = hv[1];
      *(float2*)(dout + (size_t)(b_base + bb) * ((size_t)T_STEPS * 512) + (size_t)t * 512 + u_base + u0) = ho;
      if (t == T_STEPS - 1) {
        const size_t OUT0 = (size_t)64 * 2048 * 512;
        size_t o  = OUT0 + 32768 + (size_t)(b_base + bb) * 512 + u_base + u0;
        dout[o]     = hv[0];
        dout[o + 1] = hv[1];
        size_t oc = o + 65536;
        dout[oc]     = cv[0];
        dout[oc + 1] = cv[1];
      }
    }
    __syncthreads();   // drains vmcnt: h1 stores acked at coherence point
    if (tid == 0)
      __hip_atomic_store(flp, t + 1, __ATOMIC_RELAXED, __HIP_MEMORY_SCOPE_AGENT);
  }
}

// ---------------- Fused dual-layer scan: bids 0-63 scan0, 64-127 scan1 -------------
// Deadlock-free unconditionally: scan0 never waits on scan1; all waits are on
// monotonic flags whose producers run unconditionally (scan0 reaches 2048, and
// scan1's scan0-conditions are clamped to min(.,2048)); even fully-serialized
// execution would still complete.
__global__ __launch_bounds__(256, 1) void scan_fused(
    const unsigned short* __restrict__ xg,
    const float* __restrict__ Whh0, const float* __restrict__ Whh1,
    const float* __restrict__ Wih1, const float* __restrict__ bih1,
    const float* __restrict__ bhh1,
    unsigned short* __restrict__ h0hist, unsigned short* __restrict__ h1hist,
    float* __restrict__ dout,
    int* __restrict__ flg0, int* __restrict__ flg1)
{
  extern __shared__ char smem[];
  const int bid = blockIdx.x;
  if (bid < 64)
    scan0_role(bid, xg, Whh0, h0hist, dout, flg0, smem);
  else
    scan1_role(bid - 64, Whh1, Wih1, bih1, bhh1, h0hist, h1hist, dout, flg0, flg1, smem);
}

extern "C" void kernel_launch(void* const* d_in, const int* in_sizes, int n_in,
                              void* d_out, int out_size, void* d_ws, size_t ws_size,
                              hipStream_t stream) {
  const float* x    = (const float*)d_in[0];
  const float* Wih0 = (const float*)d_in[1];
  const float* Whh0 = (const float*)d_in[2];
  const float* bih0 = (const float*)d_in[3];
  const float* bhh0 = (const float*)d_in[4];
  const float* Wih1 = (const float*)d_in[5];
  const float* Whh1 = (const float*)d_in[6];
  const float* bih1 = (const float*)d_in[7];
  const float* bhh1 = (const float*)d_in[8];
  float* out = (float*)d_out;

  const size_t XG_BYTES   = (size_t)T_STEPS * 64 * 2048 * 2;       // 536,870,912
  const size_t H_BYTES    = (size_t)(T_STEPS + 1) * 64 * 512 * 2;  // 134,283,264
  const size_t FLAG_BYTES = (size_t)2 * 4 * 16 * 32 * 4;           // 16,384 (128B/flag)
  if (ws_size < XG_BYTES + 2 * H_BYTES + FLAG_BYTES) return;

  char* ws = (char*)d_ws;
  unsigned short* xg = (unsigned short*)ws;
  unsigned short* h0 = (unsigned short*)(ws + XG_BYTES);
  unsigned short* h1 = (unsigned short*)(ws + XG_BYTES + H_BYTES);
  int* flags         = (int*)(ws + XG_BYTES + 2 * H_BYTES);
  int* flg0 = flags;
  int* flg1 = flags + 4 * 16 * 32;

  hipMemsetAsync(flags, 0, FLAG_BYTES, stream);

  const int smem_scan = 131072 + 16 * 132 * 4 + 2048;  // 141,568 B
  hipFuncSetAttribute((const void*)scan_fused, hipFuncAttributeMaxDynamicSharedMemorySize, smem_scan);

  proj_kernel<0, 1><<<dim3(16384), dim3(256), 0, stream>>>(x, Wih0, bih0, bhh0, xg);
  scan_fused<<<dim3(128), dim3(256), smem_scan, stream>>>(
      xg, Whh0, Whh1, Wih1, bih1, bhh1, h0, h1, out, flg0, flg1);
}